// Round 4
// baseline (157.364 us; speedup 1.0000x reference)
//
#include <hip/hip_runtime.h>
#include <stdint.h>
#include <stddef.h>

// b=4, n=1024, dim=512, heads=8, dh=64. qkv ws: [4096][1024] bf16 = Q|K only,
// q pre-scaled by 1/16; V transposed to vt[b][h][64][1024] bf16.

typedef __attribute__((ext_vector_type(4))) float f32x4;
typedef __attribute__((ext_vector_type(2))) float f32x2;
typedef __attribute__((ext_vector_type(8))) short bf16x8;
typedef __attribute__((ext_vector_type(4))) uint32_t u32x4;
typedef __attribute__((ext_vector_type(2))) uint32_t u32x2;

__device__ inline unsigned short f2bf(float f) {
    union { float f; uint32_t u; } cv; cv.f = f;
    uint32_t u = cv.u;
    return (unsigned short)((u + 0x7fffu + ((u >> 16) & 1u)) >> 16);
}
// HW packed convert: 2 fp32 -> 2 bf16 (RNE), single VOP3.
__device__ inline uint32_t packbf2(float lo, float hi) {
    uint32_t r;
    asm("v_cvt_pk_bf16_f32 %0, %1, %2" : "=v"(r) : "v"(lo), "v"(hi));
    return r;
}
__device__ inline void gl_lds16(const short* g, short* l) {
    __builtin_amdgcn_global_load_lds(
        (const __attribute__((address_space(1))) void*)g,
        (__attribute__((address_space(3))) void*)l, 16, 0, 0);
}
// packed-fp32 helpers -> v_pk_max_f32 / v_pk_fma_f32
__device__ inline f32x2 vmax2(f32x2 a, f32x2 b) { return __builtin_elementwise_max(a, b); }
__device__ inline f32x2 vfma2(f32x2 a, f32x2 b, f32x2 c) { return __builtin_elementwise_fma(a, b, c); }
// Pin a f32x2 into arch VGPRs (no-op at runtime; forces allocator out of AGPR).
__device__ inline void pin2(f32x2& v) {
    float a = v[0], b = v[1];
    asm("" : "+v"(a), "+v"(b));
    v[0] = a; v[1] = b;
}

// ---------------------------------------------------------------------------
// convert: x fp32 -> bf16; w_qkv [512][1536] -> wqkvt [1536][512] bf16 (T);
//          w_out [512][512] -> woutt [512][512] bf16 (T)
// ---------------------------------------------------------------------------
__global__ __launch_bounds__(256) void convert_all(const float* __restrict__ x,
                                                   const float* __restrict__ wqkv,
                                                   const float* __restrict__ wout,
                                                   short* __restrict__ xb,
                                                   short* __restrict__ wqkvt,
                                                   short* __restrict__ woutt) {
    __shared__ float tl[32][33];
    const int bid = blockIdx.x;
    const int t = threadIdx.x;
    if (bid < 1024) {
        int base = bid * 2048 + t * 8;
        f32x4 v0 = *(const f32x4*)(x + base);
        f32x4 v1 = *(const f32x4*)(x + base + 4);
        u32x4 o = {packbf2(v0[0], v0[1]), packbf2(v0[2], v0[3]),
                   packbf2(v1[0], v1[1]), packbf2(v1[2], v1[3])};
        *(u32x4*)(xb + base) = o;
        return;
    }
    const float* src; short* dst; int NC, tn, tk;
    if (bid < 1024 + 768) {
        int idx = bid - 1024; tn = idx % 48; tk = idx / 48; src = wqkv; dst = wqkvt; NC = 1536;
    } else {
        int idx = bid - 1792; tn = idx % 16; tk = idx / 16; src = wout; dst = woutt; NC = 512;
    }
    const int row = t >> 3, c4 = (t & 7) * 4;
    f32x4 v = *(const f32x4*)(src + (size_t)(tk * 32 + row) * NC + tn * 32 + c4);
    tl[row][c4 + 0] = v[0]; tl[row][c4 + 1] = v[1];
    tl[row][c4 + 2] = v[2]; tl[row][c4 + 3] = v[3];
    __syncthreads();
    float a = tl[c4 + 0][row], b = tl[c4 + 1][row];
    float c = tl[c4 + 2][row], d = tl[c4 + 3][row];
    u32x2 o = {packbf2(a, b), packbf2(c, d)};
    *(u32x2*)(dst + (size_t)(tn * 32 + row) * 512 + tk * 32 + c4) = o;
}

// ---------------------------------------------------------------------------
// bf16 MFMA GEMM: 64m x NTn tile, 256 thr (4 waves), BK=32.
// NT=128: waves 2x2 of 32x64, acc[2][4]. NT=64: waves 2x2 of 32x32, acc[2][2]
//   (R4: MODE1 was 256 blocks = 1 block/CU = 1 wave/SIMD, zero latency
//    hiding; 64-wide tiles double the grid to 512 = 2 blocks/CU).
// MODE 0: qkv_b [M][1024] (bn<4: q*1/16; bn 4..7: k) + vt scatter (bn>=8).
// MODE 1: fp32 [M][512].
// ---------------------------------------------------------------------------
template<int NB, int MODE, int NT>
__global__ __launch_bounds__(256) void gemm_bf16(const short* __restrict__ A,
                                                 const short* __restrict__ Bt,
                                                 void* __restrict__ outp,
                                                 short* __restrict__ vt) {
    constexpr int WN = NT / 2;              // per-wave n extent
    constexpr int NFR = WN / 16;            // n-fragments per wave
    __shared__ __align__(16) short As[64 * 32];
    __shared__ __align__(16) short Bs[NT * 32];
    const int t = threadIdx.x;
    const int lane = t & 63;
    const int wv = t >> 6;
    const int quad = lane >> 4;
    const int l16 = lane & 15;
    const int bm = blockIdx.x / NB;
    const int bn = blockIdx.x % NB;
    const int wm = (wv & 1) * 32, wn = (wv >> 1) * WN;

    f32x4 acc[2][NFR];
    #pragma unroll
    for (int i = 0; i < 2; i++)
        #pragma unroll
        for (int j = 0; j < NFR; j++) acc[i][j] = (f32x4){0.f, 0.f, 0.f, 0.f};

    const int sr = t >> 2, sc = (t & 3) * 8;

    for (int kt = 0; kt < 16; kt++) {
        gl_lds16(A + (size_t)(bm * 64 + sr) * 512 + kt * 32 + sc, As + t * 8);
        #pragma unroll
        for (int i = 0; i < NT / 64; i++)
            gl_lds16(Bt + (size_t)(bn * NT + 64 * i + sr) * 512 + kt * 32 + sc,
                     Bs + 64 * i * 32 + t * 8);
        __syncthreads();
        bf16x8 af[2], bfr[NFR];
        #pragma unroll
        for (int mi = 0; mi < 2; mi++)
            af[mi] = *(const bf16x8*)(As + (wm + mi * 16 + l16) * 32 + quad * 8);
        #pragma unroll
        for (int ni = 0; ni < NFR; ni++)
            bfr[ni] = *(const bf16x8*)(Bs + (wn + ni * 16 + l16) * 32 + quad * 8);
        #pragma unroll
        for (int mi = 0; mi < 2; mi++)
            #pragma unroll
            for (int ni = 0; ni < NFR; ni++)
                acc[mi][ni] = __builtin_amdgcn_mfma_f32_16x16x32_bf16(af[mi], bfr[ni], acc[mi][ni], 0, 0, 0);
        __syncthreads();
    }

    if (MODE == 0) {
        short* ob = (short*)outp;
        if (bn < 8) {
            const float scq = (bn < 4) ? 0.0625f : 1.0f;
            #pragma unroll
            for (int mi = 0; mi < 2; mi++)
                #pragma unroll
                for (int ni = 0; ni < NFR; ni++)
                    #pragma unroll
                    for (int rg = 0; rg < 4; rg++)
                        ob[(size_t)(bm * 64 + wm + mi * 16 + quad * 4 + rg) * 1024
                           + bn * NT + wn + ni * 16 + l16] = (short)f2bf(acc[mi][ni][rg] * scq);
        } else {
            #pragma unroll
            for (int mi = 0; mi < 2; mi++) {
                int rowb = bm * 64 + wm + mi * 16 + quad * 4;
                int bbb = rowb >> 10, j = rowb & 1023;
                #pragma unroll
                for (int ni = 0; ni < NFR; ni++) {
                    int vcol = bn * NT + wn + ni * 16 + l16 - 1024;   // 0..511
                    int hh = vcol >> 6, dd = vcol & 63;
                    u32x2 pk = {packbf2(acc[mi][ni][0], acc[mi][ni][1]),
                                packbf2(acc[mi][ni][2], acc[mi][ni][3])};
                    *(u32x2*)(vt + ((size_t)((bbb * 8 + hh) * 64 + dd)) * 1024 + j) = pk;
                }
            }
        }
    } else {
        float* of = (float*)outp;
        #pragma unroll
        for (int mi = 0; mi < 2; mi++)
            #pragma unroll
            for (int ni = 0; ni < NFR; ni++)
                #pragma unroll
                for (int rg = 0; rg < 4; rg++)
                    of[(size_t)(bm * 64 + wm + mi * 16 + quad * 4 + rg) * 512
                       + bn * NT + wn + ni * 16 + l16] = acc[mi][ni][rg];
    }
}

// ---------------------------------------------------------------------------
// Fused entmax-1.5 attention: 16 query rows/block, 256 thr.
// R4 changes:
//  - pin2() on zT2 after scores + at Newton-loop top: r3 showed VGPR=52 at a
//    170-reg budget => zT2(64)+zc(32) AGPR-homed (52+96=148 total = measured
//    37.5% occ). Pin forces arch-VGPR residency; tests whether AGPR access
//    from VALU costs (shuttle) or is free. Zero runtime cost either way.
//  - T14-lite: prefetch sup=0 V-frags (16 regs; 164 <= 170 budget) before
//    Newton so first PV iteration doesn't stall on L2.
// ---------------------------------------------------------------------------
__global__ __launch_bounds__(256, 3) void attn_entmax(const short* __restrict__ qkv,
                                                      const short* __restrict__ vt,
                                                      short* __restrict__ oheads) {
    __shared__ __align__(16) unsigned char smem[34304];
    short* P_lds = (short*)smem;            // [16][1024] bf16, XOR-swizzled 8-blocks (32768 B)
    float* tbuf = (float*)smem;             // [2][16][268] fp32 transpose buf (34304 B)
    float* osum = (float*)smem;             // [16][68] fp32 (4352 B)
    const int TB = 16 * 268;                // floats per tbuf chunk

    const int t = threadIdx.x;
    const int lane = t & 63;
    const int wv = t >> 6;
    const int quad = lane >> 4;
    const int l16 = lane & 15;

    const int xcd = blockIdx.x & 7;
    const int g = blockIdx.x >> 3;
    const int hb = xcd * 4 + (g >> 6);      // 0..31
    const int rt = g & 63;
    const int bb = hb >> 3, hh = hb & 7;
    const int r0 = rt * 16;

    // Q A-frags (16 real rows); q pre-scaled by 1/16 so z = sim/2 directly
    bf16x8 a0, a1;
    {
        const short* qp = qkv + (size_t)(bb * 1024 + r0 + l16) * 1024 + hh * 64 + quad * 8;
        a0 = *(const bf16x8*)qp;
        a1 = *(const bf16x8*)(qp + 32);
    }

    // ---- scores in 2 super-chunks of 512 cols, transposed to row-owner regs ----
    // zT2[ci*8 + i*2 + (c>>1)][c&1] = z[row quad*4+wv][col ci*256 + i*64 + l16*4 + c]
    f32x2 zT2[32];
    const short* kb0 = qkv + (size_t)(bb * 1024) * 1024 + 512 + hh * 64 + quad * 8;
    const int rown = quad * 4 + wv;         // owned row
    for (int sci = 0; sci < 2; sci++) {
        f32x4 zc[8];
        #pragma unroll
        for (int f = 0; f < 8; f++) {
            int ci = sci * 2 + (f >> 2);
            int ff = f & 3;
            int supl = ff >> 1, jj = ff & 1;
            int j0 = (ci * 2 + supl) * 128 + (wv + 4 * jj) * 16 + l16;
            const short* kp = kb0 + (size_t)j0 * 1024;
            bf16x8 b0 = *(const bf16x8*)kp;
            bf16x8 b1 = *(const bf16x8*)(kp + 32);
            f32x4 acc = {0.f, 0.f, 0.f, 0.f};
            acc = __builtin_amdgcn_mfma_f32_16x16x32_bf16(a0, b0, acc, 0, 0, 0);
            acc = __builtin_amdgcn_mfma_f32_16x16x32_bf16(a1, b1, acc, 0, 0, 0);
            zc[f] = acc;
        }
        __syncthreads();                    // previous super-chunk's readback complete
        #pragma unroll
        for (int f = 0; f < 8; f++) {
            int c2 = f >> 2, ff = f & 3;
            int supl = ff >> 1, jj = ff & 1;
            int colc = supl * 128 + (wv + 4 * jj) * 16 + l16;
            #pragma unroll
            for (int rg = 0; rg < 4; rg++)
                tbuf[c2 * TB + (quad * 4 + rg) * 268 + colc] = zc[f][rg];
        }
        __syncthreads();
        #pragma unroll
        for (int c2 = 0; c2 < 2; c2++)
            #pragma unroll
            for (int i = 0; i < 4; i++) {
                f32x4 v = *(const f32x4*)(tbuf + c2 * TB + rown * 268 + i * 64 + l16 * 4);
                int ci = sci * 2 + c2;
                zT2[ci * 8 + i * 2 + 0] = (f32x2){v[0], v[1]};
                zT2[ci * 8 + i * 2 + 1] = (f32x2){v[2], v[3]};
            }
    }
    __syncthreads();                        // last readback done; smem reusable

    // Force zT2 into arch VGPRs (r3: allocator homed it in AGPRs at VGPR=52).
    #pragma unroll
    for (int i = 0; i < 32; i++) pin2(zT2[i]);

    // T14-lite: issue sup=0 V loads now; consumed after the P barrier.
    const short* vb0 = vt + (size_t)((bb * 8 + hh) * 64) * 1024;
    bf16x8 vpre[4];
    #pragma unroll
    for (int nt = 0; nt < 4; nt++)
        vpre[nt] = *(const bf16x8*)(vb0 + (size_t)(nt * 16 + l16) * 1024 + wv * 32 + quad * 8);

    // ---- init: mx + full-support closed-form tau, clamped to bracket ----
    float tau;
    {
        f32x2 m2 = zT2[0], p2 = zT2[0];
        f32x2 q2 = zT2[0] * zT2[0];
        #pragma unroll
        for (int i = 1; i < 32; i++) {
            f32x2 v = zT2[i];
            m2 = vmax2(m2, v);
            p2 = p2 + v;
            q2 = vfma2(v, v, q2);
        }
        float mx = fmaxf(m2[0], m2[1]);
        float s1 = p2[0] + p2[1];
        float s2 = q2[0] + q2[1];
        #pragma unroll
        for (int s = 1; s < 16; s <<= 1) {
            mx = fmaxf(mx, __shfl_xor(mx, s, 64));
            s1 += __shfl_xor(s1, s, 64);
            s2 += __shfl_xor(s2, s, 64);
        }
        float mean = s1 * (1.0f / 1024.0f);
        float disc = fmaxf(mean * mean - (s2 - 1.0f) * (1.0f / 1024.0f), 0.0f);
        tau = mean - __builtin_sqrtf(disc);
        tau = fminf(tau, mx - 0.03125f);    // tau* <= mx - 1/sqrt(n)
        tau = fmaxf(tau, mx - 1.0f);        // tau* >= mx - 1
    }

    // ---- Newton (barrier-free, packed fp32): f(tau)=sum relu(z-tau)^2 - 1 ----
    const f32x2 zero2 = {0.f, 0.f};
    #pragma unroll 1
    for (int it = 0; it < 7; it++) {
        #pragma unroll
        for (int i = 0; i < 32; i++) pin2(zT2[i]);   // keep VGPR-resident
        f32x2 tau2 = {tau, tau};
        f32x2 s1a = zero2, s1b = zero2, s2a = zero2, s2b = zero2;
        #pragma unroll
        for (int i = 0; i < 16; i++) {
            f32x2 ra = vmax2(zT2[i * 2] - tau2, zero2);
            f32x2 rb = vmax2(zT2[i * 2 + 1] - tau2, zero2);
            s1a = s1a + ra; s1b = s1b + rb;
            s2a = vfma2(ra, ra, s2a); s2b = vfma2(rb, rb, s2b);
        }
        float s1 = (s1a[0] + s1a[1]) + (s1b[0] + s1b[1]);
        float s2 = (s2a[0] + s2a[1]) + (s2b[0] + s2b[1]);
        #pragma unroll
        for (int s = 1; s < 16; s <<= 1) {
            s1 += __shfl_xor(s1, s, 64);
            s2 += __shfl_xor(s2, s, 64);
        }
        tau += (s2 - 1.0f) * 0.5f * __builtin_amdgcn_rcpf(s1);
    }

    // ---- P = relu(z-tau)^2 -> swizzled P_lds (bf16, A-operand layout) ----
    // off(row, j) = row*1024 + ((jb ^ (row&7))<<3) + (j&7), jb = j>>3
    {
        const f32x2 tau2 = {tau, tau};
        const int dg = l16;
        const int ra = rown & 7;
        #pragma unroll
        for (int ci = 0; ci < 4; ci++)
            #pragma unroll
            for (int i = 0; i < 4; i++) {
                f32x2 r01 = vmax2(zT2[ci * 8 + i * 2] - tau2, zero2);
                f32x2 r23 = vmax2(zT2[ci * 8 + i * 2 + 1] - tau2, zero2);
                f32x2 p01 = r01 * r01, p23 = r23 * r23;
                u32x2 pk = {packbf2(p01[0], p01[1]), packbf2(p23[0], p23[1])};
                int jb = ci * 32 + i * 8 + (dg >> 1);
                *(u32x2*)(P_lds + rown * 1024 + ((jb ^ ra) << 3) + (dg & 1) * 4) = pk;
            }
    }
    __syncthreads();

    // ---- PV from global V^T: O[r][d] += P[r][j] V[j][d] ----
    f32x4 oacc[4];
    #pragma unroll
    for (int nt = 0; nt < 4; nt++) oacc[nt] = (f32x4){0.f, 0.f, 0.f, 0.f};
    const int lra = l16 & 7;
    #pragma unroll
    for (int sup = 0; sup < 8; sup++) {
        int jb = sup * 16 + wv * 4 + quad;
        bf16x8 pf = *(const bf16x8*)(P_lds + l16 * 1024 + ((jb ^ lra) << 3));
        #pragma unroll
        for (int nt = 0; nt < 4; nt++) {
            bf16x8 bv = (sup == 0) ? vpre[nt]
                      : *(const bf16x8*)(vb0 + (size_t)(nt * 16 + l16) * 1024
                                         + sup * 128 + wv * 32 + quad * 8);
            oacc[nt] = __builtin_amdgcn_mfma_f32_16x16x32_bf16(pf, bv, oacc[nt], 0, 0, 0);
        }
    }
    __syncthreads();                        // all P reads done; overlay osum

    #pragma unroll
    for (int nt = 0; nt < 4; nt++)
        #pragma unroll
        for (int rg = 0; rg < 4; rg++)
            osum[(wv * 16 + quad * 4 + rg) * 68 + nt * 16 + l16] = oacc[nt][rg];
    __syncthreads();
    #pragma unroll
    for (int i = 0; i < 2; i++) {
        int idx = t + 256 * i;
        int r = idx >> 5, dp = idx & 31;
        float e0 = 0.f, e1 = 0.f;
        #pragma unroll
        for (int w = 0; w < 4; w++) {
            e0 += osum[(w * 16 + r) * 68 + dp * 2];
            e1 += osum[(w * 16 + r) * 68 + dp * 2 + 1];
        }
        *(uint32_t*)(oheads + (size_t)(bb * 1024 + r0 + r) * 512 + hh * 64 + dp * 2) = packbf2(e0, e1);
    }
}

// ---------------------------------------------------------------------------
extern "C" void kernel_launch(void* const* d_in, const int* in_sizes, int n_in,
                              void* d_out, int out_size, void* d_ws, size_t ws_size,
                              hipStream_t stream) {
    (void)in_sizes; (void)n_in; (void)out_size; (void)ws_size;
    const float* x     = (const float*)d_in[0];
    const float* w_qkv = (const float*)d_in[1];
    const float* w_out = (const float*)d_in[2];
    float* out = (float*)d_out;

    char* ws = (char*)d_ws;
    short* qkv_b = (short*)(ws);                        // 8,388,608 B (Q|K)
    short* vt    = (short*)(ws + 8388608);              // 4,194,304 B (V^T)
    short* ohead = (short*)(ws + 12582912);             // 4,194,304 B
    short* xb    = (short*)(ws + 16777216);             // 4,194,304 B
    short* wqkvt = (short*)(ws + 20971520);             // 1,572,864 B
    short* woutt = (short*)(ws + 22544384);             //   524,288 B

    convert_all<<<dim3(2048), dim3(256), 0, stream>>>(x, w_qkv, w_out, xb, wqkvt, woutt);
    gemm_bf16<12, 0, 128><<<dim3(64 * 12), dim3(256), 0, stream>>>(xb, wqkvt, (void*)qkv_b, vt);
    attn_entmax<<<dim3(2048), dim3(256), 0, stream>>>(qkv_b, vt, ohead);
    gemm_bf16<8, 1, 64><<<dim3(64 * 8), dim3(256), 0, stream>>>(ohead, woutt, (void*)out, nullptr);
}

// Round 5
// 151.277 us; speedup vs baseline: 1.0402x; 1.0402x over previous
//
#include <hip/hip_runtime.h>
#include <stdint.h>
#include <stddef.h>

// b=4, n=1024, dim=512, heads=8, dh=64. qkv ws: [4096][1024] bf16 = Q|K only,
// q pre-scaled by 1/16; V transposed to vt[b][h][64][1024] bf16.

typedef __attribute__((ext_vector_type(4))) float f32x4;
typedef __attribute__((ext_vector_type(2))) float f32x2;
typedef __attribute__((ext_vector_type(8))) short bf16x8;
typedef __attribute__((ext_vector_type(4))) uint32_t u32x4;
typedef __attribute__((ext_vector_type(2))) uint32_t u32x2;

__device__ inline unsigned short f2bf(float f) {
    union { float f; uint32_t u; } cv; cv.f = f;
    uint32_t u = cv.u;
    return (unsigned short)((u + 0x7fffu + ((u >> 16) & 1u)) >> 16);
}
// HW packed convert: 2 fp32 -> 2 bf16 (RNE), single VOP3.
__device__ inline uint32_t packbf2(float lo, float hi) {
    uint32_t r;
    asm("v_cvt_pk_bf16_f32 %0, %1, %2" : "=v"(r) : "v"(lo), "v"(hi));
    return r;
}
__device__ inline void gl_lds16(const short* g, short* l) {
    __builtin_amdgcn_global_load_lds(
        (const __attribute__((address_space(1))) void*)g,
        (__attribute__((address_space(3))) void*)l, 16, 0, 0);
}
// packed-fp32 helpers -> v_pk_max_f32 / v_pk_fma_f32
__device__ inline f32x2 vmax2(f32x2 a, f32x2 b) { return __builtin_elementwise_max(a, b); }
__device__ inline f32x2 vfma2(f32x2 a, f32x2 b, f32x2 c) { return __builtin_elementwise_fma(a, b, c); }

// ---------------------------------------------------------------------------
// convert: x fp32 -> bf16; w_qkv [512][1536] -> wqkvt [1536][512] bf16 (T);
//          w_out [512][512] -> woutt [512][512] bf16 (T)
// ---------------------------------------------------------------------------
__global__ __launch_bounds__(256) void convert_all(const float* __restrict__ x,
                                                   const float* __restrict__ wqkv,
                                                   const float* __restrict__ wout,
                                                   short* __restrict__ xb,
                                                   short* __restrict__ wqkvt,
                                                   short* __restrict__ woutt) {
    __shared__ float tl[32][33];
    const int bid = blockIdx.x;
    const int t = threadIdx.x;
    if (bid < 1024) {
        int base = bid * 2048 + t * 8;
        f32x4 v0 = *(const f32x4*)(x + base);
        f32x4 v1 = *(const f32x4*)(x + base + 4);
        u32x4 o = {packbf2(v0[0], v0[1]), packbf2(v0[2], v0[3]),
                   packbf2(v1[0], v1[1]), packbf2(v1[2], v1[3])};
        *(u32x4*)(xb + base) = o;
        return;
    }
    const float* src; short* dst; int NC, tn, tk;
    if (bid < 1024 + 768) {
        int idx = bid - 1024; tn = idx % 48; tk = idx / 48; src = wqkv; dst = wqkvt; NC = 1536;
    } else {
        int idx = bid - 1792; tn = idx % 16; tk = idx / 16; src = wout; dst = woutt; NC = 512;
    }
    const int row = t >> 3, c4 = (t & 7) * 4;
    f32x4 v = *(const f32x4*)(src + (size_t)(tk * 32 + row) * NC + tn * 32 + c4);
    tl[row][c4 + 0] = v[0]; tl[row][c4 + 1] = v[1];
    tl[row][c4 + 2] = v[2]; tl[row][c4 + 3] = v[3];
    __syncthreads();
    float a = tl[c4 + 0][row], b = tl[c4 + 1][row];
    float c = tl[c4 + 2][row], d = tl[c4 + 3][row];
    u32x2 o = {packbf2(a, b), packbf2(c, d)};
    *(u32x2*)(dst + (size_t)(tn * 32 + row) * 512 + tk * 32 + c4) = o;
}

// ---------------------------------------------------------------------------
// bf16 MFMA GEMM: 64m x NTn tile, 256 thr (4 waves), BK=32.
// NT=128: waves 2x2 of 32x64, acc[2][4]. NT=64: waves 2x2 of 32x32, acc[2][2]
//   (MODE1 at NT=128 was 256 blocks = 1 block/CU = 1 wave/SIMD; NT=64 doubles
//    the grid to 512 = 2 blocks/CU — r4 showed total-minus-attn improved).
// MODE 0: qkv_b [M][1024] (bn<4: q*1/16; bn 4..7: k) + vt scatter (bn>=8).
// MODE 1: fp32 [M][512].
// ---------------------------------------------------------------------------
template<int NB, int MODE, int NT>
__global__ __launch_bounds__(256) void gemm_bf16(const short* __restrict__ A,
                                                 const short* __restrict__ Bt,
                                                 void* __restrict__ outp,
                                                 short* __restrict__ vt) {
    constexpr int WN = NT / 2;              // per-wave n extent
    constexpr int NFR = WN / 16;            // n-fragments per wave
    __shared__ __align__(16) short As[64 * 32];
    __shared__ __align__(16) short Bs[NT * 32];
    const int t = threadIdx.x;
    const int lane = t & 63;
    const int wv = t >> 6;
    const int quad = lane >> 4;
    const int l16 = lane & 15;
    const int bm = blockIdx.x / NB;
    const int bn = blockIdx.x % NB;
    const int wm = (wv & 1) * 32, wn = (wv >> 1) * WN;

    f32x4 acc[2][NFR];
    #pragma unroll
    for (int i = 0; i < 2; i++)
        #pragma unroll
        for (int j = 0; j < NFR; j++) acc[i][j] = (f32x4){0.f, 0.f, 0.f, 0.f};

    const int sr = t >> 2, sc = (t & 3) * 8;

    for (int kt = 0; kt < 16; kt++) {
        gl_lds16(A + (size_t)(bm * 64 + sr) * 512 + kt * 32 + sc, As + t * 8);
        #pragma unroll
        for (int i = 0; i < NT / 64; i++)
            gl_lds16(Bt + (size_t)(bn * NT + 64 * i + sr) * 512 + kt * 32 + sc,
                     Bs + 64 * i * 32 + t * 8);
        __syncthreads();
        bf16x8 af[2], bfr[NFR];
        #pragma unroll
        for (int mi = 0; mi < 2; mi++)
            af[mi] = *(const bf16x8*)(As + (wm + mi * 16 + l16) * 32 + quad * 8);
        #pragma unroll
        for (int ni = 0; ni < NFR; ni++)
            bfr[ni] = *(const bf16x8*)(Bs + (wn + ni * 16 + l16) * 32 + quad * 8);
        #pragma unroll
        for (int mi = 0; mi < 2; mi++)
            #pragma unroll
            for (int ni = 0; ni < NFR; ni++)
                acc[mi][ni] = __builtin_amdgcn_mfma_f32_16x16x32_bf16(af[mi], bfr[ni], acc[mi][ni], 0, 0, 0);
        __syncthreads();
    }

    if (MODE == 0) {
        short* ob = (short*)outp;
        if (bn < 8) {
            const float scq = (bn < 4) ? 0.0625f : 1.0f;
            #pragma unroll
            for (int mi = 0; mi < 2; mi++)
                #pragma unroll
                for (int ni = 0; ni < NFR; ni++)
                    #pragma unroll
                    for (int rg = 0; rg < 4; rg++)
                        ob[(size_t)(bm * 64 + wm + mi * 16 + quad * 4 + rg) * 1024
                           + bn * NT + wn + ni * 16 + l16] = (short)f2bf(acc[mi][ni][rg] * scq);
        } else {
            #pragma unroll
            for (int mi = 0; mi < 2; mi++) {
                int rowb = bm * 64 + wm + mi * 16 + quad * 4;
                int bbb = rowb >> 10, j = rowb & 1023;
                #pragma unroll
                for (int ni = 0; ni < NFR; ni++) {
                    int vcol = bn * NT + wn + ni * 16 + l16 - 1024;   // 0..511
                    int hh = vcol >> 6, dd = vcol & 63;
                    u32x2 pk = {packbf2(acc[mi][ni][0], acc[mi][ni][1]),
                                packbf2(acc[mi][ni][2], acc[mi][ni][3])};
                    *(u32x2*)(vt + ((size_t)((bbb * 8 + hh) * 64 + dd)) * 1024 + j) = pk;
                }
            }
        }
    } else {
        float* of = (float*)outp;
        #pragma unroll
        for (int mi = 0; mi < 2; mi++)
            #pragma unroll
            for (int ni = 0; ni < NFR; ni++)
                #pragma unroll
                for (int rg = 0; rg < 4; rg++)
                    of[(size_t)(bm * 64 + wm + mi * 16 + quad * 4 + rg) * 512
                       + bn * NT + wn + ni * 16 + l16] = acc[mi][ni][rg];
    }
}

// ---------------------------------------------------------------------------
// Fused entmax-1.5 attention: 16 query rows/block, 256 thr.
// R5: occupancy recombination. Perf tracks occupancy (r1-r4 record); r3's
// 2-superchunk zc[8] holds 32 AGPRs -> 148 regs/thread -> 3 blocks/CU. Revert
// to 4-chunk score phase (zc[4], 16 AGPRs): 48V + 16A + 64A(zT2) = 128 regs
// -> 4 blocks/CU; LDS back to 32768 (tbuf [16][268] single buffer). Keep all
// r3 wins (cvt_pk pack, rolled Newton, no setprio); pin2/vpre removed (r4:
// -1 block occupancy, +9us).
// ---------------------------------------------------------------------------
__global__ __launch_bounds__(256, 4) void attn_entmax(const short* __restrict__ qkv,
                                                      const short* __restrict__ vt,
                                                      short* __restrict__ oheads) {
    __shared__ __align__(16) unsigned char smem[32768];
    short* P_lds = (short*)smem;            // [16][1024] bf16, XOR-swizzled 8-blocks (32768 B)
    float* tbuf = (float*)smem;             // [16][268] fp32 transpose buf (17152 B)
    float* osum = (float*)smem;             // [16][68] fp32 (4352 B)

    const int t = threadIdx.x;
    const int lane = t & 63;
    const int wv = t >> 6;
    const int quad = lane >> 4;
    const int l16 = lane & 15;

    const int xcd = blockIdx.x & 7;
    const int g = blockIdx.x >> 3;
    const int hb = xcd * 4 + (g >> 6);      // 0..31
    const int rt = g & 63;
    const int bb = hb >> 3, hh = hb & 7;
    const int r0 = rt * 16;

    // Q A-frags (16 real rows); q pre-scaled by 1/16 so z = sim/2 directly
    bf16x8 a0, a1;
    {
        const short* qp = qkv + (size_t)(bb * 1024 + r0 + l16) * 1024 + hh * 64 + quad * 8;
        a0 = *(const bf16x8*)qp;
        a1 = *(const bf16x8*)(qp + 32);
    }

    // ---- scores in 4 column-chunks of 256, transposed to row-owner layout ----
    // zT2[ci*8 + i*2 + (c>>1)][c&1] = z[row quad*4+wv][col ci*256 + i*64 + l16*4 + c]
    f32x2 zT2[32];
    const short* kb0 = qkv + (size_t)(bb * 1024) * 1024 + 512 + hh * 64 + quad * 8;
    const int rown = quad * 4 + wv;         // owned row
    for (int ci = 0; ci < 4; ci++) {
        f32x4 zc[4];
        #pragma unroll
        for (int f = 0; f < 4; f++) {
            int supl = f >> 1, jj = f & 1;
            int j0 = (ci * 2 + supl) * 128 + (wv + 4 * jj) * 16 + l16;
            const short* kp = kb0 + (size_t)j0 * 1024;
            bf16x8 b0 = *(const bf16x8*)kp;
            bf16x8 b1 = *(const bf16x8*)(kp + 32);
            f32x4 acc = {0.f, 0.f, 0.f, 0.f};
            acc = __builtin_amdgcn_mfma_f32_16x16x32_bf16(a0, b0, acc, 0, 0, 0);
            acc = __builtin_amdgcn_mfma_f32_16x16x32_bf16(a1, b1, acc, 0, 0, 0);
            zc[f] = acc;
        }
        __syncthreads();                    // previous chunk's readback complete
        #pragma unroll
        for (int f = 0; f < 4; f++) {
            int supl = f >> 1, jj = f & 1;
            int colc = supl * 128 + (wv + 4 * jj) * 16 + l16;
            #pragma unroll
            for (int rg = 0; rg < 4; rg++)
                tbuf[(quad * 4 + rg) * 268 + colc] = zc[f][rg];
        }
        __syncthreads();
        #pragma unroll
        for (int i = 0; i < 4; i++) {
            f32x4 v = *(const f32x4*)(tbuf + rown * 268 + i * 64 + l16 * 4);
            zT2[ci * 8 + i * 2 + 0] = (f32x2){v[0], v[1]};
            zT2[ci * 8 + i * 2 + 1] = (f32x2){v[2], v[3]};
        }
    }
    __syncthreads();                        // last readback done; smem reusable

    // ---- init: mx + full-support closed-form tau, clamped to bracket ----
    float tau;
    {
        f32x2 m2 = zT2[0], p2 = zT2[0];
        f32x2 q2 = zT2[0] * zT2[0];
        #pragma unroll
        for (int i = 1; i < 32; i++) {
            f32x2 v = zT2[i];
            m2 = vmax2(m2, v);
            p2 = p2 + v;
            q2 = vfma2(v, v, q2);
        }
        float mx = fmaxf(m2[0], m2[1]);
        float s1 = p2[0] + p2[1];
        float s2 = q2[0] + q2[1];
        #pragma unroll
        for (int s = 1; s < 16; s <<= 1) {
            mx = fmaxf(mx, __shfl_xor(mx, s, 64));
            s1 += __shfl_xor(s1, s, 64);
            s2 += __shfl_xor(s2, s, 64);
        }
        float mean = s1 * (1.0f / 1024.0f);
        float disc = fmaxf(mean * mean - (s2 - 1.0f) * (1.0f / 1024.0f), 0.0f);
        tau = mean - __builtin_sqrtf(disc);
        tau = fminf(tau, mx - 0.03125f);    // tau* <= mx - 1/sqrt(n)
        tau = fmaxf(tau, mx - 1.0f);        // tau* >= mx - 1
    }

    // ---- Newton (barrier-free, packed fp32): f(tau)=sum relu(z-tau)^2 - 1 ----
    const f32x2 zero2 = {0.f, 0.f};
    #pragma unroll 1
    for (int it = 0; it < 7; it++) {
        f32x2 tau2 = {tau, tau};
        f32x2 s1a = zero2, s1b = zero2, s2a = zero2, s2b = zero2;
        #pragma unroll
        for (int i = 0; i < 16; i++) {
            f32x2 ra = vmax2(zT2[i * 2] - tau2, zero2);
            f32x2 rb = vmax2(zT2[i * 2 + 1] - tau2, zero2);
            s1a = s1a + ra; s1b = s1b + rb;
            s2a = vfma2(ra, ra, s2a); s2b = vfma2(rb, rb, s2b);
        }
        float s1 = (s1a[0] + s1a[1]) + (s1b[0] + s1b[1]);
        float s2 = (s2a[0] + s2a[1]) + (s2b[0] + s2b[1]);
        #pragma unroll
        for (int s = 1; s < 16; s <<= 1) {
            s1 += __shfl_xor(s1, s, 64);
            s2 += __shfl_xor(s2, s, 64);
        }
        tau += (s2 - 1.0f) * 0.5f * __builtin_amdgcn_rcpf(s1);
    }

    // ---- P = relu(z-tau)^2 -> swizzled P_lds (bf16, A-operand layout) ----
    // off(row, j) = row*1024 + ((jb ^ (row&7))<<3) + (j&7), jb = j>>3
    {
        const f32x2 tau2 = {tau, tau};
        const int dg = l16;
        const int ra = rown & 7;
        #pragma unroll
        for (int ci = 0; ci < 4; ci++)
            #pragma unroll
            for (int i = 0; i < 4; i++) {
                f32x2 r01 = vmax2(zT2[ci * 8 + i * 2] - tau2, zero2);
                f32x2 r23 = vmax2(zT2[ci * 8 + i * 2 + 1] - tau2, zero2);
                f32x2 p01 = r01 * r01, p23 = r23 * r23;
                u32x2 pk = {packbf2(p01[0], p01[1]), packbf2(p23[0], p23[1])};
                int jb = ci * 32 + i * 8 + (dg >> 1);
                *(u32x2*)(P_lds + rown * 1024 + ((jb ^ ra) << 3) + (dg & 1) * 4) = pk;
            }
    }
    __syncthreads();

    // ---- PV from global V^T: O[r][d] += P[r][j] V[j][d] ----
    f32x4 oacc[4];
    #pragma unroll
    for (int nt = 0; nt < 4; nt++) oacc[nt] = (f32x4){0.f, 0.f, 0.f, 0.f};
    const short* vb0 = vt + (size_t)((bb * 8 + hh) * 64) * 1024;
    const int lra = l16 & 7;
    #pragma unroll
    for (int sup = 0; sup < 8; sup++) {
        int jb = sup * 16 + wv * 4 + quad;
        bf16x8 pf = *(const bf16x8*)(P_lds + l16 * 1024 + ((jb ^ lra) << 3));
        #pragma unroll
        for (int nt = 0; nt < 4; nt++) {
            bf16x8 bv = *(const bf16x8*)(vb0 + (size_t)(nt * 16 + l16) * 1024
                                         + sup * 128 + wv * 32 + quad * 8);
            oacc[nt] = __builtin_amdgcn_mfma_f32_16x16x32_bf16(pf, bv, oacc[nt], 0, 0, 0);
        }
    }
    __syncthreads();                        // all P reads done; overlay osum

    #pragma unroll
    for (int nt = 0; nt < 4; nt++)
        #pragma unroll
        for (int rg = 0; rg < 4; rg++)
            osum[(wv * 16 + quad * 4 + rg) * 68 + nt * 16 + l16] = oacc[nt][rg];
    __syncthreads();
    #pragma unroll
    for (int i = 0; i < 2; i++) {
        int idx = t + 256 * i;
        int r = idx >> 5, dp = idx & 31;
        float e0 = 0.f, e1 = 0.f;
        #pragma unroll
        for (int w = 0; w < 4; w++) {
            e0 += osum[(w * 16 + r) * 68 + dp * 2];
            e1 += osum[(w * 16 + r) * 68 + dp * 2 + 1];
        }
        *(uint32_t*)(oheads + (size_t)(bb * 1024 + r0 + r) * 512 + hh * 64 + dp * 2) = packbf2(e0, e1);
    }
}

// ---------------------------------------------------------------------------
extern "C" void kernel_launch(void* const* d_in, const int* in_sizes, int n_in,
                              void* d_out, int out_size, void* d_ws, size_t ws_size,
                              hipStream_t stream) {
    (void)in_sizes; (void)n_in; (void)out_size; (void)ws_size;
    const float* x     = (const float*)d_in[0];
    const float* w_qkv = (const float*)d_in[1];
    const float* w_out = (const float*)d_in[2];
    float* out = (float*)d_out;

    char* ws = (char*)d_ws;
    short* qkv_b = (short*)(ws);                        // 8,388,608 B (Q|K)
    short* vt    = (short*)(ws + 8388608);              // 4,194,304 B (V^T)
    short* ohead = (short*)(ws + 12582912);             // 4,194,304 B
    short* xb    = (short*)(ws + 16777216);             // 4,194,304 B
    short* wqkvt = (short*)(ws + 20971520);             // 1,572,864 B
    short* woutt = (short*)(ws + 22544384);             //   524,288 B

    convert_all<<<dim3(2048), dim3(256), 0, stream>>>(x, w_qkv, w_out, xb, wqkvt, woutt);
    gemm_bf16<12, 0, 128><<<dim3(64 * 12), dim3(256), 0, stream>>>(xb, wqkvt, (void*)qkv_b, vt);
    attn_entmax<<<dim3(2048), dim3(256), 0, stream>>>(qkv_b, vt, ohead);
    gemm_bf16<8, 1, 64><<<dim3(64 * 8), dim3(256), 0, stream>>>(ohead, woutt, (void*)out, nullptr);
}

// Round 6
// 126.497 us; speedup vs baseline: 1.2440x; 1.1959x over previous
//
#include <hip/hip_runtime.h>
#include <stdint.h>
#include <stddef.h>

// b=4, n=1024, dim=512, heads=8, dh=64.
// R6 layouts (fragment-native, fixes 64-line gathers in attn):
//   qb  [4096][512]  bf16  Q, pre-scaled 1/16
//   kh  [b*8+h][j/16][8 dhb][16 j][8 dh] bf16  (128 KB/head)
//   vt3 [b*8+h][j/8][64 d][8 j] bf16           (128 KB/head)

typedef __attribute__((ext_vector_type(4))) float f32x4;
typedef __attribute__((ext_vector_type(2))) float f32x2;
typedef __attribute__((ext_vector_type(8))) short bf16x8;
typedef __attribute__((ext_vector_type(4))) uint32_t u32x4;
typedef __attribute__((ext_vector_type(2))) uint32_t u32x2;

__device__ inline unsigned short f2bf(float f) {
    union { float f; uint32_t u; } cv; cv.f = f;
    uint32_t u = cv.u;
    return (unsigned short)((u + 0x7fffu + ((u >> 16) & 1u)) >> 16);
}
// HW packed convert: 2 fp32 -> 2 bf16 (RNE), single VOP3.
__device__ inline uint32_t packbf2(float lo, float hi) {
    uint32_t r;
    asm("v_cvt_pk_bf16_f32 %0, %1, %2" : "=v"(r) : "v"(lo), "v"(hi));
    return r;
}
__device__ inline void gl_lds16(const short* g, short* l) {
    __builtin_amdgcn_global_load_lds(
        (const __attribute__((address_space(1))) void*)g,
        (__attribute__((address_space(3))) void*)l, 16, 0, 0);
}
// packed-fp32 helpers -> v_pk_max_f32 / v_pk_fma_f32
__device__ inline f32x2 vmax2(f32x2 a, f32x2 b) { return __builtin_elementwise_max(a, b); }
__device__ inline f32x2 vfma2(f32x2 a, f32x2 b, f32x2 c) { return __builtin_elementwise_fma(a, b, c); }

// ---------------------------------------------------------------------------
// convert: x fp32 -> bf16; w_qkv [512][1536] -> wqkvt [1536][512] bf16 (T);
//          w_out [512][512] -> woutt [512][512] bf16 (T)
// ---------------------------------------------------------------------------
__global__ __launch_bounds__(256) void convert_all(const float* __restrict__ x,
                                                   const float* __restrict__ wqkv,
                                                   const float* __restrict__ wout,
                                                   short* __restrict__ xb,
                                                   short* __restrict__ wqkvt,
                                                   short* __restrict__ woutt) {
    __shared__ float tl[32][33];
    const int bid = blockIdx.x;
    const int t = threadIdx.x;
    if (bid < 1024) {
        int base = bid * 2048 + t * 8;
        f32x4 v0 = *(const f32x4*)(x + base);
        f32x4 v1 = *(const f32x4*)(x + base + 4);
        u32x4 o = {packbf2(v0[0], v0[1]), packbf2(v0[2], v0[3]),
                   packbf2(v1[0], v1[1]), packbf2(v1[2], v1[3])};
        *(u32x4*)(xb + base) = o;
        return;
    }
    const float* src; short* dst; int NC, tn, tk;
    if (bid < 1024 + 768) {
        int idx = bid - 1024; tn = idx % 48; tk = idx / 48; src = wqkv; dst = wqkvt; NC = 1536;
    } else {
        int idx = bid - 1792; tn = idx % 16; tk = idx / 16; src = wout; dst = woutt; NC = 512;
    }
    const int row = t >> 3, c4 = (t & 7) * 4;
    f32x4 v = *(const f32x4*)(src + (size_t)(tk * 32 + row) * NC + tn * 32 + c4);
    tl[row][c4 + 0] = v[0]; tl[row][c4 + 1] = v[1];
    tl[row][c4 + 2] = v[2]; tl[row][c4 + 3] = v[3];
    __syncthreads();
    float a = tl[c4 + 0][row], b = tl[c4 + 1][row];
    float c = tl[c4 + 2][row], d = tl[c4 + 3][row];
    u32x2 o = {packbf2(a, b), packbf2(c, d)};
    *(u32x2*)(dst + (size_t)(tn * 32 + row) * 512 + tk * 32 + c4) = o;
}

// ---------------------------------------------------------------------------
// bf16 MFMA GEMM: 64m x NTn tile, 256 thr (4 waves), BK=32.
// MODE 0: bn<4 -> qb [M][512] (q*1/16); bn 4..7 -> kh frag-layout;
//         bn>=8 -> vt3 frag-layout.
// MODE 1: fp32 [M][512].
// ---------------------------------------------------------------------------
template<int NB, int MODE, int NT>
__global__ __launch_bounds__(256) void gemm_bf16(const short* __restrict__ A,
                                                 const short* __restrict__ Bt,
                                                 void* __restrict__ outp,
                                                 short* __restrict__ vt3,
                                                 short* __restrict__ kh) {
    constexpr int WN = NT / 2;              // per-wave n extent
    constexpr int NFR = WN / 16;            // n-fragments per wave
    __shared__ __align__(16) short As[64 * 32];
    __shared__ __align__(16) short Bs[NT * 32];
    const int t = threadIdx.x;
    const int lane = t & 63;
    const int wv = t >> 6;
    const int quad = lane >> 4;
    const int l16 = lane & 15;
    const int bm = blockIdx.x / NB;
    const int bn = blockIdx.x % NB;
    const int wm = (wv & 1) * 32, wn = (wv >> 1) * WN;

    f32x4 acc[2][NFR];
    #pragma unroll
    for (int i = 0; i < 2; i++)
        #pragma unroll
        for (int j = 0; j < NFR; j++) acc[i][j] = (f32x4){0.f, 0.f, 0.f, 0.f};

    const int sr = t >> 2, sc = (t & 3) * 8;

    for (int kt = 0; kt < 16; kt++) {
        gl_lds16(A + (size_t)(bm * 64 + sr) * 512 + kt * 32 + sc, As + t * 8);
        #pragma unroll
        for (int i = 0; i < NT / 64; i++)
            gl_lds16(Bt + (size_t)(bn * NT + 64 * i + sr) * 512 + kt * 32 + sc,
                     Bs + 64 * i * 32 + t * 8);
        __syncthreads();
        bf16x8 af[2], bfr[NFR];
        #pragma unroll
        for (int mi = 0; mi < 2; mi++)
            af[mi] = *(const bf16x8*)(As + (wm + mi * 16 + l16) * 32 + quad * 8);
        #pragma unroll
        for (int ni = 0; ni < NFR; ni++)
            bfr[ni] = *(const bf16x8*)(Bs + (wn + ni * 16 + l16) * 32 + quad * 8);
        #pragma unroll
        for (int mi = 0; mi < 2; mi++)
            #pragma unroll
            for (int ni = 0; ni < NFR; ni++)
                acc[mi][ni] = __builtin_amdgcn_mfma_f32_16x16x32_bf16(af[mi], bfr[ni], acc[mi][ni], 0, 0, 0);
        __syncthreads();
    }

    if (MODE == 0) {
        if (bn < 4) {
            // Q -> qb [4096][512], scaled 1/16
            short* ob = (short*)outp;
            #pragma unroll
            for (int mi = 0; mi < 2; mi++)
                #pragma unroll
                for (int ni = 0; ni < NFR; ni++)
                    #pragma unroll
                    for (int rg = 0; rg < 4; rg++)
                        ob[(size_t)(bm * 64 + wm + mi * 16 + quad * 4 + rg) * 512
                           + bn * NT + wn + ni * 16 + l16] = (short)f2bf(acc[mi][ni][rg] * 0.0625f);
        } else if (bn < 8) {
            // K -> kh frag layout: head (bb,hh): [j>>4][dh>>3][j&15][dh&7]
            #pragma unroll
            for (int mi = 0; mi < 2; mi++) {
                int rowb = bm * 64 + wm + mi * 16 + quad * 4;   // +rg later (same j>>4)
                int bbb = rowb >> 10, jj0 = rowb & 1023;
                #pragma unroll
                for (int ni = 0; ni < NFR; ni++) {
                    int c = bn * NT + wn + ni * 16 + l16 - 512;  // 0..511
                    int hh = c >> 6, dh = c & 63;
                    short* base = kh + (size_t)(bbb * 8 + hh) * 65536
                                  + (size_t)(jj0 >> 4) * 1024 + (dh >> 3) * 128 + (dh & 7);
                    #pragma unroll
                    for (int rg = 0; rg < 4; rg++)
                        base[((jj0 & 15) + rg) * 8] = (short)f2bf(acc[mi][ni][rg]);
                }
            }
        } else {
            // V -> vt3 frag layout: head: [j>>3][d][j&7]
            #pragma unroll
            for (int mi = 0; mi < 2; mi++) {
                int rowb = bm * 64 + wm + mi * 16 + quad * 4;
                int bbb = rowb >> 10, j = rowb & 1023;
                #pragma unroll
                for (int ni = 0; ni < NFR; ni++) {
                    int vcol = bn * NT + wn + ni * 16 + l16 - 1024;  // 0..511
                    int hh = vcol >> 6, dd = vcol & 63;
                    u32x2 pk = {packbf2(acc[mi][ni][0], acc[mi][ni][1]),
                                packbf2(acc[mi][ni][2], acc[mi][ni][3])};
                    *(u32x2*)(vt3 + (size_t)(bbb * 8 + hh) * 65536
                              + (size_t)(j >> 3) * 512 + dd * 8 + (j & 7)) = pk;
                }
            }
        }
    } else {
        float* of = (float*)outp;
        #pragma unroll
        for (int mi = 0; mi < 2; mi++)
            #pragma unroll
            for (int ni = 0; ni < NFR; ni++)
                #pragma unroll
                for (int rg = 0; rg < 4; rg++)
                    of[(size_t)(bm * 64 + wm + mi * 16 + quad * 4 + rg) * 512
                       + bn * NT + wn + ni * 16 + l16] = acc[mi][ni][rg];
    }
}

// ---------------------------------------------------------------------------
// Fused entmax-1.5 attention: 16 query rows/block, 256 thr.
// R6: compute structure identical to r5; ONLY the K/V global loads change to
// fragment-native layouts. Theory: r1-r5 all-pipes-idle + occupancy-
// insensitivity = vector-memory address-pipe serialization from 64-line
// gathers (per-lane 2KB row stride). kh: each B-frag load = 1KB contiguous;
// vt3: 4x256B segments. ~10x fewer L2 lines/transactions per wave.
// ---------------------------------------------------------------------------
__global__ __launch_bounds__(256, 4) void attn_entmax(const short* __restrict__ qb,
                                                      const short* __restrict__ kh,
                                                      const short* __restrict__ vt3,
                                                      short* __restrict__ oheads) {
    __shared__ __align__(16) unsigned char smem[32768];
    short* P_lds = (short*)smem;            // [16][1024] bf16, XOR-swizzled 8-blocks (32768 B)
    float* tbuf = (float*)smem;             // [16][268] fp32 transpose buf (17152 B)
    float* osum = (float*)smem;             // [16][68] fp32 (4352 B)

    const int t = threadIdx.x;
    const int lane = t & 63;
    const int wv = t >> 6;
    const int quad = lane >> 4;
    const int l16 = lane & 15;

    const int xcd = blockIdx.x & 7;
    const int g = blockIdx.x >> 3;
    const int hb = xcd * 4 + (g >> 6);      // 0..31
    const int rt = g & 63;
    const int bb = hb >> 3, hh = hb & 7;
    const int r0 = rt * 16;

    // Q A-frags from qb [4096][512]; q pre-scaled by 1/16 so z = sim/2
    bf16x8 a0, a1;
    {
        const short* qp = qb + (size_t)(bb * 1024 + r0 + l16) * 512 + hh * 64 + quad * 8;
        a0 = *(const bf16x8*)qp;
        a1 = *(const bf16x8*)(qp + 32);
    }

    const short* khh = kh + (size_t)(bb * 8 + hh) * 65536;
    const short* vb0 = vt3 + (size_t)(bb * 8 + hh) * 65536;

    // ---- scores in 4 column-chunks of 256, transposed to row-owner layout ----
    // zT2[ci*8 + i*2 + (c>>1)][c&1] = z[row quad*4+wv][col ci*256 + i*64 + l16*4 + c]
    f32x2 zT2[32];
    const int rown = quad * 4 + wv;         // owned row
    for (int ci = 0; ci < 4; ci++) {
        f32x4 zc[4];
        #pragma unroll
        for (int f = 0; f < 4; f++) {
            int supl = f >> 1, jj = f & 1;
            int jtile = (ci * 2 + supl) * 8 + (wv + 4 * jj);
            // kh frag-layout: b0 = K[jtile*16+l16][quad*8..+7], b1 = +32 dh
            const short* kp = khh + (size_t)jtile * 1024 + l16 * 8;
            bf16x8 b0 = *(const bf16x8*)(kp + quad * 128);
            bf16x8 b1 = *(const bf16x8*)(kp + (4 + quad) * 128);
            f32x4 acc = {0.f, 0.f, 0.f, 0.f};
            acc = __builtin_amdgcn_mfma_f32_16x16x32_bf16(a0, b0, acc, 0, 0, 0);
            acc = __builtin_amdgcn_mfma_f32_16x16x32_bf16(a1, b1, acc, 0, 0, 0);
            zc[f] = acc;
        }
        __syncthreads();                    // previous chunk's readback complete
        #pragma unroll
        for (int f = 0; f < 4; f++) {
            int supl = f >> 1, jj = f & 1;
            int colc = supl * 128 + (wv + 4 * jj) * 16 + l16;
            #pragma unroll
            for (int rg = 0; rg < 4; rg++)
                tbuf[(quad * 4 + rg) * 268 + colc] = zc[f][rg];
        }
        __syncthreads();
        #pragma unroll
        for (int i = 0; i < 4; i++) {
            f32x4 v = *(const f32x4*)(tbuf + rown * 268 + i * 64 + l16 * 4);
            zT2[ci * 8 + i * 2 + 0] = (f32x2){v[0], v[1]};
            zT2[ci * 8 + i * 2 + 1] = (f32x2){v[2], v[3]};
        }
    }
    __syncthreads();                        // last readback done; smem reusable

    // ---- init: mx + full-support closed-form tau, clamped to bracket ----
    float tau;
    {
        f32x2 m2 = zT2[0], p2 = zT2[0];
        f32x2 q2 = zT2[0] * zT2[0];
        #pragma unroll
        for (int i = 1; i < 32; i++) {
            f32x2 v = zT2[i];
            m2 = vmax2(m2, v);
            p2 = p2 + v;
            q2 = vfma2(v, v, q2);
        }
        float mx = fmaxf(m2[0], m2[1]);
        float s1 = p2[0] + p2[1];
        float s2 = q2[0] + q2[1];
        #pragma unroll
        for (int s = 1; s < 16; s <<= 1) {
            mx = fmaxf(mx, __shfl_xor(mx, s, 64));
            s1 += __shfl_xor(s1, s, 64);
            s2 += __shfl_xor(s2, s, 64);
        }
        float mean = s1 * (1.0f / 1024.0f);
        float disc = fmaxf(mean * mean - (s2 - 1.0f) * (1.0f / 1024.0f), 0.0f);
        tau = mean - __builtin_sqrtf(disc);
        tau = fminf(tau, mx - 0.03125f);    // tau* <= mx - 1/sqrt(n)
        tau = fmaxf(tau, mx - 1.0f);        // tau* >= mx - 1
    }

    // ---- Newton (barrier-free, packed fp32): f(tau)=sum relu(z-tau)^2 - 1 ----
    const f32x2 zero2 = {0.f, 0.f};
    #pragma unroll 1
    for (int it = 0; it < 7; it++) {
        f32x2 tau2 = {tau, tau};
        f32x2 s1a = zero2, s1b = zero2, s2a = zero2, s2b = zero2;
        #pragma unroll
        for (int i = 0; i < 16; i++) {
            f32x2 ra = vmax2(zT2[i * 2] - tau2, zero2);
            f32x2 rb = vmax2(zT2[i * 2 + 1] - tau2, zero2);
            s1a = s1a + ra; s1b = s1b + rb;
            s2a = vfma2(ra, ra, s2a); s2b = vfma2(rb, rb, s2b);
        }
        float s1 = (s1a[0] + s1a[1]) + (s1b[0] + s1b[1]);
        float s2 = (s2a[0] + s2a[1]) + (s2b[0] + s2b[1]);
        #pragma unroll
        for (int s = 1; s < 16; s <<= 1) {
            s1 += __shfl_xor(s1, s, 64);
            s2 += __shfl_xor(s2, s, 64);
        }
        tau += (s2 - 1.0f) * 0.5f * __builtin_amdgcn_rcpf(s1);
    }

    // ---- P = relu(z-tau)^2 -> swizzled P_lds (bf16, A-operand layout) ----
    // off(row, j) = row*1024 + ((jb ^ (row&7))<<3) + (j&7), jb = j>>3
    {
        const f32x2 tau2 = {tau, tau};
        const int dg = l16;
        const int ra = rown & 7;
        #pragma unroll
        for (int ci = 0; ci < 4; ci++)
            #pragma unroll
            for (int i = 0; i < 4; i++) {
                f32x2 r01 = vmax2(zT2[ci * 8 + i * 2] - tau2, zero2);
                f32x2 r23 = vmax2(zT2[ci * 8 + i * 2 + 1] - tau2, zero2);
                f32x2 p01 = r01 * r01, p23 = r23 * r23;
                u32x2 pk = {packbf2(p01[0], p01[1]), packbf2(p23[0], p23[1])};
                int jb = ci * 32 + i * 8 + (dg >> 1);
                *(u32x2*)(P_lds + rown * 1024 + ((jb ^ ra) << 3) + (dg & 1) * 4) = pk;
            }
    }
    __syncthreads();

    // ---- PV from vt3 frag layout: O[r][d] += P[r][j] V[j][d] ----
    f32x4 oacc[4];
    #pragma unroll
    for (int nt = 0; nt < 4; nt++) oacc[nt] = (f32x4){0.f, 0.f, 0.f, 0.f};
    const int lra = l16 & 7;
    #pragma unroll
    for (int sup = 0; sup < 8; sup++) {
        int jb = sup * 16 + wv * 4 + quad;
        bf16x8 pf = *(const bf16x8*)(P_lds + l16 * 1024 + ((jb ^ lra) << 3));
        const short* vs = vb0 + (size_t)jb * 512;       // [jb][64 d][8 j]
        #pragma unroll
        for (int nt = 0; nt < 4; nt++) {
            bf16x8 bv = *(const bf16x8*)(vs + (nt * 16 + l16) * 8);
            oacc[nt] = __builtin_amdgcn_mfma_f32_16x16x32_bf16(pf, bv, oacc[nt], 0, 0, 0);
        }
    }
    __syncthreads();                        // all P reads done; overlay osum

    #pragma unroll
    for (int nt = 0; nt < 4; nt++)
        #pragma unroll
        for (int rg = 0; rg < 4; rg++)
            osum[(wv * 16 + quad * 4 + rg) * 68 + nt * 16 + l16] = oacc[nt][rg];
    __syncthreads();
    #pragma unroll
    for (int i = 0; i < 2; i++) {
        int idx = t + 256 * i;
        int r = idx >> 5, dp = idx & 31;
        float e0 = 0.f, e1 = 0.f;
        #pragma unroll
        for (int w = 0; w < 4; w++) {
            e0 += osum[(w * 16 + r) * 68 + dp * 2];
            e1 += osum[(w * 16 + r) * 68 + dp * 2 + 1];
        }
        *(uint32_t*)(oheads + (size_t)(bb * 1024 + r0 + r) * 512 + hh * 64 + dp * 2) = packbf2(e0, e1);
    }
}

// ---------------------------------------------------------------------------
extern "C" void kernel_launch(void* const* d_in, const int* in_sizes, int n_in,
                              void* d_out, int out_size, void* d_ws, size_t ws_size,
                              hipStream_t stream) {
    (void)in_sizes; (void)n_in; (void)out_size; (void)ws_size;
    const float* x     = (const float*)d_in[0];
    const float* w_qkv = (const float*)d_in[1];
    const float* w_out = (const float*)d_in[2];
    float* out = (float*)d_out;

    char* ws = (char*)d_ws;
    short* qb    = (short*)(ws);                        // 4,194,304 B  Q [4096][512]
    short* kh    = (short*)(ws + 4194304);              // 4,194,304 B  K frag-layout
    short* vt3   = (short*)(ws + 8388608);              // 4,194,304 B  V frag-layout
    short* ohead = (short*)(ws + 12582912);             // 4,194,304 B
    short* xb    = (short*)(ws + 16777216);             // 4,194,304 B
    short* wqkvt = (short*)(ws + 20971520);             // 1,572,864 B
    short* woutt = (short*)(ws + 22544384);             //   524,288 B

    convert_all<<<dim3(2048), dim3(256), 0, stream>>>(x, w_qkv, w_out, xb, wqkvt, woutt);
    gemm_bf16<12, 0, 128><<<dim3(64 * 12), dim3(256), 0, stream>>>(xb, wqkvt, (void*)qb, vt3, kh);
    attn_entmax<<<dim3(2048), dim3(256), 0, stream>>>(qb, kh, vt3, ohead);
    gemm_bf16<8, 1, 64><<<dim3(64 * 8), dim3(256), 0, stream>>>(ohead, woutt, (void*)out, nullptr, nullptr);
}